// Round 2
// baseline (1786.633 us; speedup 1.0000x reference)
//
#include <hip/hip_runtime.h>
#include <hip/hip_bf16.h>
#include <math.h>

// TrittentionCube: B=2, T=192, N_HEADS=8, D_MODEL=512, D_HEAD=64, fp32.
//
// Pipeline:
//  k_proj : a,b,c,d,e[b,p,n,h] = x @ W_{A..E} + bias          (5x GEMM 384x512x512)
//  k_bsum : bsum[b,q,j] = sum_n b[b,q,n,j]        (step2 of reference sums over n)
//  k_step1: step1[b,r,(i,j)] = c[(b,r),(n,k)] @ W_K[(n,k),(i,j)]   (384x4096x512)
//  k_step2: step2[b,(r,i),q] = step1[b,(r,i),j] @ bsum[b,q,j]^T    (12288x192x64 x2)
//  k_attn : per (b,n,r): S[p,q] = (1/64) a[p,:]·st2[r,:,q], valid iff p<q & p<r;
//           E = exp(S); F[p,g] = E@e; U[h,g] = sum_p d[p,h] F[p,g];
//           z[k] = sum_{h,g} U[h,g] W_V[n,h,g,k] / sum(E).  r==0 -> z=0.
//  k_out  : out = z[(b,r),(n,h)] @ W_O + b_O                       (384x512x512)

#define OFF_A      0u
#define OFF_Bp     196608u
#define OFF_C      393216u
#define OFF_D      589824u
#define OFF_E      786432u
#define OFF_BSUM   983040u          // [2][192][64]
#define OFF_S1     1007616u         // [384][4096]
#define OFF_S2     2580480u         // [2][12288][192]
#define OFF_Z      7299072u         // [384][512]

// ---------------- shared 64x64x16 fp32 tile GEMM helpers ----------------

__device__ __forceinline__ void load_At(const float* __restrict__ Aptr, int lda,
                                        float* __restrict__ As, int t) {
  // 64 rows x 16 k, stored transposed As[k*68 + row]
  int r = t >> 2, c4 = (t & 3) * 4;
  const float4 v = *(const float4*)(Aptr + r * lda + c4);
  As[(c4 + 0) * 68 + r] = v.x;
  As[(c4 + 1) * 68 + r] = v.y;
  As[(c4 + 2) * 68 + r] = v.z;
  As[(c4 + 3) * 68 + r] = v.w;
}

__device__ __forceinline__ void mm_acc16(const float* __restrict__ As,
                                         const float* __restrict__ Bs,
                                         float acc[4][4], int tm4, int tn4) {
#pragma unroll
  for (int kk = 0; kk < 16; ++kk) {
    const float4 a = *(const float4*)(As + kk * 68 + tm4);
    const float4 b = *(const float4*)(Bs + kk * 68 + tn4);
    acc[0][0] += a.x * b.x; acc[0][1] += a.x * b.y; acc[0][2] += a.x * b.z; acc[0][3] += a.x * b.w;
    acc[1][0] += a.y * b.x; acc[1][1] += a.y * b.y; acc[1][2] += a.y * b.z; acc[1][3] += a.y * b.w;
    acc[2][0] += a.z * b.x; acc[2][1] += a.z * b.y; acc[2][2] += a.z * b.z; acc[2][3] += a.z * b.w;
    acc[3][0] += a.w * b.x; acc[3][1] += a.w * b.y; acc[3][2] += a.w * b.z; acc[3][3] += a.w * b.w;
  }
}

// ---------------- k_proj: 5 projections ----------------

__global__ void k_proj(const float* __restrict__ x,
                       const float* __restrict__ W0, const float* __restrict__ W1,
                       const float* __restrict__ W2, const float* __restrict__ W3,
                       const float* __restrict__ W4,
                       const float* __restrict__ bi0, const float* __restrict__ bi1,
                       const float* __restrict__ bi2, const float* __restrict__ bi3,
                       const float* __restrict__ bi4,
                       float* __restrict__ ws) {
  const int wsel = blockIdx.z;
  const float* W = wsel == 0 ? W0 : wsel == 1 ? W1 : wsel == 2 ? W2 : wsel == 3 ? W3 : W4;
  const float* bias = wsel == 0 ? bi0 : wsel == 1 ? bi1 : wsel == 2 ? bi2 : wsel == 3 ? bi3 : bi4;
  float* out = ws + (size_t)wsel * 196608u;

  const int m0 = blockIdx.x * 64;   // over 384 rows (b,p)
  const int c0 = blockIdx.y * 64;   // over 512 cols (n,h)
  const int nblk = c0 >> 6;
  __shared__ float As[16 * 68], Bs[16 * 68];
  const int t = threadIdx.x;
  const int tm4 = (t >> 4) * 4, tn4 = (t & 15) * 4;
  float acc[4][4] = {};

  for (int k0 = 0; k0 < 512; k0 += 16) {
    load_At(x + m0 * 512 + k0, 512, As, t);
#pragma unroll
    for (int it = 0; it < 4; ++it) {
      int kk = (t >> 6) + it * 4, cc = t & 63;
      Bs[kk * 68 + cc] = W[nblk * 32768 + (k0 + kk) * 64 + cc];  // W[n,d,h]
    }
    __syncthreads();
    mm_acc16(As, Bs, acc, tm4, tn4);
    __syncthreads();
  }
  const float4 bv = *(const float4*)&bias[c0 + tn4];
#pragma unroll
  for (int i = 0; i < 4; ++i) {
    float4 v;
    v.x = acc[i][0] + bv.x; v.y = acc[i][1] + bv.y; v.z = acc[i][2] + bv.z; v.w = acc[i][3] + bv.w;
    *(float4*)&out[(m0 + tm4 + i) * 512 + c0 + tn4] = v;
  }
}

// ---------------- k_bsum ----------------

__global__ void k_bsum(const float* __restrict__ bp, float* __restrict__ out) {
  int idx = blockIdx.x * 256 + threadIdx.x;   // 2*192*64 = 24576
  if (idx < 24576) {
    int bq = idx >> 6, j = idx & 63;
    float s = 0.f;
#pragma unroll
    for (int n = 0; n < 8; ++n) s += bp[bq * 512 + n * 64 + j];
    out[idx] = s;
  }
}

// ---------------- k_step1: M=384 N=4096 K=512 ----------------

__global__ void k_step1(const float* __restrict__ Cp, const float* __restrict__ WK,
                        float* __restrict__ S1) {
  const int m0 = blockIdx.x * 64, c0 = blockIdx.y * 64;
  __shared__ float As[16 * 68], Bs[16 * 68];
  const int t = threadIdx.x;
  const int tm4 = (t >> 4) * 4, tn4 = (t & 15) * 4;
  float acc[4][4] = {};
  for (int k0 = 0; k0 < 512; k0 += 16) {
    load_At(Cp + m0 * 512 + k0, 512, As, t);
#pragma unroll
    for (int it = 0; it < 4; ++it) {
      int kk = t & 15, cc = (t >> 4) + it * 16;
      int k = k0 + kk;  // (n,kk): W_K[n,i,j,k] -> B[(n,k)][(i,j)]
      Bs[kk * 68 + cc] = WK[(k >> 6) * 262144 + (c0 + cc) * 64 + (k & 63)];
    }
    __syncthreads();
    mm_acc16(As, Bs, acc, tm4, tn4);
    __syncthreads();
  }
#pragma unroll
  for (int i = 0; i < 4; ++i) {
    float4 v; v.x = acc[i][0]; v.y = acc[i][1]; v.z = acc[i][2]; v.w = acc[i][3];
    *(float4*)&S1[(size_t)(m0 + tm4 + i) * 4096 + c0 + tn4] = v;
  }
}

// ---------------- k_step2: per b, M=12288 N=192 K=64 ----------------

__global__ void k_step2(const float* __restrict__ S1, const float* __restrict__ BS,
                        float* __restrict__ S2) {
  const int b = blockIdx.z;
  const int m0 = blockIdx.x * 64, c0 = blockIdx.y * 64;
  const float* A = S1 + (size_t)b * 786432u;   // [(r,i)][j], lda 64
  const float* Bb = BS + b * 12288;            // bsum[b][q][j]
  float* C = S2 + (size_t)b * 2359296u;        // [(r,i)][q]
  __shared__ float As[16 * 68], Bs[16 * 68];
  const int t = threadIdx.x;
  const int tm4 = (t >> 4) * 4, tn4 = (t & 15) * 4;
  float acc[4][4] = {};
  for (int k0 = 0; k0 < 64; k0 += 16) {
    load_At(A + m0 * 64 + k0, 64, As, t);
#pragma unroll
    for (int it = 0; it < 4; ++it) {
      int kk = t & 15, cc = (t >> 4) + it * 16;
      Bs[kk * 68 + cc] = Bb[(c0 + cc) * 64 + k0 + kk];
    }
    __syncthreads();
    mm_acc16(As, Bs, acc, tm4, tn4);
    __syncthreads();
  }
#pragma unroll
  for (int i = 0; i < 4; ++i) {
    float4 v; v.x = acc[i][0]; v.y = acc[i][1]; v.z = acc[i][2]; v.w = acc[i][3];
    *(float4*)&C[(size_t)(m0 + tm4 + i) * 192 + c0 + tn4] = v;
  }
}

// ---------------- k_attn: fused scores/softmax/F/U/z per (b,n,r) ----------------
// dynamic LDS layout (floats):
#define L_ST2 0u               // [64][196]  st2_s[i][q]
#define L_ES  12544u           // [192][68]  e_s[q][g]
#define L_EXP 25600u           // [16][193]  E_s[pl][q]
#define L_AS  28688u           // [16][68]   a_s[pl][i]
#define L_DS  29776u           // [16][64]   d_s[pl][h]
#define L_FS  30800u           // [16][68]   F_s[pl][g]
#define L_RED 31888u           // [256]
#define L_TOT 32144u           // 128576 bytes (< 160 KiB)
#define L_U   L_ST2            // epilogue reuse: U[g][68+h], 4352 floats

extern "C" __global__ void __launch_bounds__(256, 1)
k_attn(const float* __restrict__ st2, const float* __restrict__ eproj,
       const float* __restrict__ aproj, const float* __restrict__ dproj,
       const float* __restrict__ WV, float* __restrict__ zout) {
  extern __shared__ float sm[];
  const int bn = blockIdx.x;               // n = bn&7 -> XCD id (linear%8), L2-pins W_V[n]
  const int r = 191 - blockIdx.y;          // heavy blocks first
  const int b = bn >> 3, n = bn & 7;
  const int t = threadIdx.x;

  const float* st2g = st2 + (size_t)b * 2359296u + (size_t)r * 12288u;  // [i][q] ld 192
  const float* eg = eproj + (size_t)b * 98304u + n * 64;                // + q*512 + g
  const float* ag = aproj + (size_t)b * 98304u + n * 64;                // + p*512 + i
  const float* dg = dproj + (size_t)b * 98304u + n * 64;                // + p*512 + h

  // stage step2 tile [64][192] -> stride 196
  for (int idx = t; idx < 64 * 48; idx += 256) {
    int i = idx / 48, q4 = (idx - i * 48) * 4;
    const float4 v = *(const float4*)(st2g + i * 192 + q4);
    *(float4*)&sm[L_ST2 + i * 196 + q4] = v;
  }
  // stage e tile [192][64] -> stride 68
  for (int idx = t; idx < 192 * 16; idx += 256) {
    int q = idx >> 4, g4 = (idx & 15) * 4;
    const float4 v = *(const float4*)(eg + q * 512 + g4);
    *(float4*)&sm[L_ES + q * 68 + g4] = v;
  }

  float Dpart = 0.f;
  float U_reg[16];
#pragma unroll
  for (int i = 0; i < 16; ++i) U_reg[i] = 0.f;

  const int h64 = t & 63, w = t >> 6, s16 = (t >> 6) * 16;
  const int pl16 = t >> 4, q16 = t & 15;
  const int ptiles = (r + 15) >> 4;

  for (int pt = 0; pt < ptiles; ++pt) {
    const int p0 = pt << 4;
    __syncthreads();
    { // stage a,d tiles [16][*]
      int row = t >> 4, c4 = (t & 15) * 4;
      *(float4*)&sm[L_AS + row * 68 + c4] = *(const float4*)(ag + (p0 + row) * 512 + c4);
      *(float4*)&sm[L_DS + row * 64 + c4] = *(const float4*)(dg + (p0 + row) * 512 + c4);
    }
    __syncthreads();
    { // scores + exp: thread owns (pl16, q = 32g + 2*q16 + u)
      const int p = p0 + pl16;
      float Sv[12];
#pragma unroll
      for (int j = 0; j < 12; ++j) Sv[j] = 0.f;
      const float* arow = &sm[L_AS + pl16 * 68];
      for (int i = 0; i < 64; ++i) {
        const float av = arow[i];
        const float* row = &sm[L_ST2 + i * 196 + 2 * q16];
#pragma unroll
        for (int g = 0; g < 6; ++g) {
          const float2 sv = *(const float2*)(row + 32 * g);
          Sv[2 * g] += av * sv.x;
          Sv[2 * g + 1] += av * sv.y;
        }
      }
      const bool pv = (p < r);
#pragma unroll
      for (int g = 0; g < 6; ++g) {
#pragma unroll
        for (int u = 0; u < 2; ++u) {
          const int q = 32 * g + 2 * q16 + u;
          float Ev = 0.f;
          if (pv && q > p) { Ev = __expf(Sv[2 * g + u] * 0.015625f); Dpart += Ev; }
          sm[L_EXP + pl16 * 193 + q] = Ev;
        }
      }
    }
    __syncthreads();
    const int plmax = min(16, r - p0);
    { // F[pl][g] = sum_q E[pl][q] * e[q][g]; thread owns (pl16, g=4*q16..+3)
      float f0 = 0.f, f1 = 0.f, f2 = 0.f, f3 = 0.f;
      if (pl16 < plmax) {
        const float* Er = &sm[L_EXP + pl16 * 193];
        for (int q = 0; q < 192; ++q) {
          const float Ev = Er[q];
          const float4 ev = *(const float4*)&sm[L_ES + q * 68 + q16 * 4];
          f0 += Ev * ev.x; f1 += Ev * ev.y; f2 += Ev * ev.z; f3 += Ev * ev.w;
        }
      }
      float4 fv; fv.x = f0; fv.y = f1; fv.z = f2; fv.w = f3;
      *(float4*)&sm[L_FS + pl16 * 68 + q16 * 4] = fv;   // zeros for invalid rows
    }
    __syncthreads();
    { // U[h,g] += sum_pl d[pl][h] * F[pl][g]; thread owns (h64, g in [s16,s16+16))
#pragma unroll 4
      for (int pl = 0; pl < 16; ++pl) {   // F rows >= plmax are zero -> safe
        const float dv = sm[L_DS + pl * 64 + h64];
        const float* Fr = &sm[L_FS + pl * 68 + s16];
#pragma unroll
        for (int gg = 0; gg < 16; ++gg) U_reg[gg] += dv * Fr[gg];
      }
    }
  }

  // ---- denominator reduction ----
  __syncthreads();
  sm[L_RED + t] = Dpart;
  __syncthreads();
  for (int off = 128; off > 0; off >>= 1) {
    if (t < off) sm[L_RED + t] += sm[L_RED + t + off];
    __syncthreads();
  }
  const float D = sm[L_RED];
  __syncthreads();   // everyone has D; L_RED and L_ST2 (as L_U) now reusable

  float* zrow = zout + (size_t)(b * 192 + r) * 512 + n * 64;
  if (D > 0.f) {
    // store U to LDS as U[g][h] (stride 68)
#pragma unroll
    for (int gg = 0; gg < 16; ++gg) sm[L_U + (s16 + gg) * 68 + h64] = U_reg[gg];
    __syncthreads();
    // z[k] = sum_{h,g} U[h,g] * W_V[n,h,g,k]; thread owns (k=h64, h in [s16,s16+16))
    const float* WVn = WV + (size_t)n * 262144u;
    float zp = 0.f;
    for (int hh = s16; hh < s16 + 16; ++hh) {
      const float* wr = WVn + hh * 4096 + h64;   // + g*64
#pragma unroll 8
      for (int g = 0; g < 64; ++g) {
        zp += sm[L_U + g * 68 + hh] * wr[g * 64];
      }
    }
    sm[L_RED + t] = zp;
    __syncthreads();
    if (t < 64) {
      float z = sm[L_RED + t] + sm[L_RED + 64 + t] + sm[L_RED + 128 + t] + sm[L_RED + 192 + t];
      zrow[t] = z / D;
    }
  } else {
    if (t < 64) zrow[t] = 0.f;   // r==0: fully masked row -> probs all on extra col -> z=0
  }
}

// ---------------- k_out: out = z @ W_O + b_O  (384x512x512) ----------------

__global__ void k_out(const float* __restrict__ Z, const float* __restrict__ WO,
                      const float* __restrict__ bO, float* __restrict__ out) {
  const int m0 = blockIdx.x * 64, c0 = blockIdx.y * 64;
  __shared__ float As[16 * 68], Bs[16 * 68];
  const int t = threadIdx.x;
  const int tm4 = (t >> 4) * 4, tn4 = (t & 15) * 4;
  float acc[4][4] = {};
  for (int k0 = 0; k0 < 512; k0 += 16) {
    load_At(Z + m0 * 512 + k0, 512, As, t);
#pragma unroll
    for (int it = 0; it < 4; ++it) {
      int kk = (t >> 6) + it * 4, cc = t & 63;
      Bs[kk * 68 + cc] = WO[(k0 + kk) * 512 + c0 + cc];
    }
    __syncthreads();
    mm_acc16(As, Bs, acc, tm4, tn4);
    __syncthreads();
  }
  const float4 bv = *(const float4*)&bO[c0 + tn4];
#pragma unroll
  for (int i = 0; i < 4; ++i) {
    float4 v;
    v.x = acc[i][0] + bv.x; v.y = acc[i][1] + bv.y; v.z = acc[i][2] + bv.z; v.w = acc[i][3] + bv.w;
    *(float4*)&out[(m0 + tm4 + i) * 512 + c0 + tn4] = v;
  }
}

// ---------------- launch ----------------

extern "C" void kernel_launch(void* const* d_in, const int* in_sizes, int n_in,
                              void* d_out, int out_size, void* d_ws, size_t ws_size,
                              hipStream_t stream) {
  const float* x  = (const float*)d_in[0];
  const float* WA = (const float*)d_in[1];
  const float* WB = (const float*)d_in[2];
  const float* WC = (const float*)d_in[3];
  const float* WD = (const float*)d_in[4];
  const float* WE = (const float*)d_in[5];
  const float* WK = (const float*)d_in[6];
  const float* WV = (const float*)d_in[7];
  const float* WO = (const float*)d_in[8];
  const float* bA = (const float*)d_in[9];
  const float* bB = (const float*)d_in[10];
  const float* bC = (const float*)d_in[11];
  const float* bD = (const float*)d_in[12];
  const float* bE = (const float*)d_in[13];
  const float* bO = (const float*)d_in[14];
  float* ws = (float*)d_ws;
  float* out = (float*)d_out;

  dim3 blk(256);
  k_proj<<<dim3(6, 8, 5), blk, 0, stream>>>(x, WA, WB, WC, WD, WE, bA, bB, bC, bD, bE, ws);
  k_bsum<<<dim3(96), blk, 0, stream>>>(ws + OFF_Bp, ws + OFF_BSUM);
  k_step1<<<dim3(6, 64), blk, 0, stream>>>(ws + OFF_C, WK, ws + OFF_S1);
  k_step2<<<dim3(192, 3, 2), blk, 0, stream>>>(ws + OFF_S1, ws + OFF_BSUM, ws + OFF_S2);

  const int attn_lds = (int)(L_TOT * sizeof(float));   // ~125.6 KB (gfx950: 160 KB/CU)
  hipFuncSetAttribute((const void*)k_attn, hipFuncAttributeMaxDynamicSharedMemorySize, attn_lds);
  k_attn<<<dim3(16, 192), blk, attn_lds, stream>>>(ws + OFF_S2, ws + OFF_E, ws + OFF_A,
                                                   ws + OFF_D, WV, ws + OFF_Z);

  k_out<<<dim3(6, 8), blk, 0, stream>>>(ws + OFF_Z, WO, bO, out);
}

// Round 8
// 440.911 us; speedup vs baseline: 4.0521x; 4.0521x over previous
//
#include <hip/hip_runtime.h>
#include <hip/hip_bf16.h>
#include <math.h>

// TrittentionCube: B=2, T=192, N_HEADS=8, D_MODEL=512, D_HEAD=64, fp32 in/out.
//
//  k_proj : a,b,c,d,e[b,p,n,h] = x @ W_{A..E} + bias          (5x GEMM 384x512x512)
//  k_bsum : bsum[b,q,j] = sum_n b[b,q,n,j]
//  k_step1: step1[b,r,(i,j)] = c[(b,r),(n,k)] @ W_K[(n,k),(i,j)]
//  k_step2: step2[b,(r,i),q] = step1[b,(r,i),j] @ bsum[b,q,j]^T
//  k_attn : per (b,n,r) block, bf16 MFMA:
//           GEMM1' S_T[q][p] = st2_t[q][i] . a[p][i]  (mask p<r & q>p, exp -> E bf16)
//           GEMM2  F[p][g]   = E[p][q] . e_t[g][q]    -> F_t[g][p] bf16
//           GEMM3  U[h][g]  += d_t[h][p] . F_t[g][p]  (fp32 frags, across p-tiles)
//           z[k] = sum_{h,g} U[h,g] W_V[n,h,g,k] / sum(E); r==0 -> 0
//  k_out  : out = z @ W_O + b_O

#define OFF_A      0u
#define OFF_Bp     196608u
#define OFF_C      393216u
#define OFF_D      589824u
#define OFF_E      786432u
#define OFF_BSUM   983040u
#define OFF_S1     1007616u
#define OFF_S2     2580480u
#define OFF_Z      7299072u

typedef short s8v __attribute__((ext_vector_type(8)));
typedef float f4v __attribute__((ext_vector_type(4)));

static __device__ __forceinline__ unsigned short f2bf(float f) {
  union { float f; unsigned int u; } v; v.f = f;
  unsigned int r = v.u + 0x7FFFu + ((v.u >> 16) & 1u);
  return (unsigned short)(r >> 16);
}

// ---------------- shared 64x64x16 fp32 tile GEMM helpers ----------------

__device__ __forceinline__ void load_At(const float* __restrict__ Aptr, int lda,
                                        float* __restrict__ As, int t) {
  int r = t >> 2, c4 = (t & 3) * 4;
  const float4 v = *(const float4*)(Aptr + r * lda + c4);
  As[(c4 + 0) * 68 + r] = v.x;
  As[(c4 + 1) * 68 + r] = v.y;
  As[(c4 + 2) * 68 + r] = v.z;
  As[(c4 + 3) * 68 + r] = v.w;
}

__device__ __forceinline__ void mm_acc16(const float* __restrict__ As,
                                         const float* __restrict__ Bs,
                                         float acc[4][4], int tm4, int tn4) {
#pragma unroll
  for (int kk = 0; kk < 16; ++kk) {
    const float4 a = *(const float4*)(As + kk * 68 + tm4);
    const float4 b = *(const float4*)(Bs + kk * 68 + tn4);
    acc[0][0] += a.x * b.x; acc[0][1] += a.x * b.y; acc[0][2] += a.x * b.z; acc[0][3] += a.x * b.w;
    acc[1][0] += a.y * b.x; acc[1][1] += a.y * b.y; acc[1][2] += a.y * b.z; acc[1][3] += a.y * b.w;
    acc[2][0] += a.z * b.x; acc[2][1] += a.z * b.y; acc[2][2] += a.z * b.z; acc[2][3] += a.z * b.w;
    acc[3][0] += a.w * b.x; acc[3][1] += a.w * b.y; acc[3][2] += a.w * b.z; acc[3][3] += a.w * b.w;
  }
}

// ---------------- k_proj ----------------

__global__ void k_proj(const float* __restrict__ x,
                       const float* __restrict__ W0, const float* __restrict__ W1,
                       const float* __restrict__ W2, const float* __restrict__ W3,
                       const float* __restrict__ W4,
                       const float* __restrict__ bi0, const float* __restrict__ bi1,
                       const float* __restrict__ bi2, const float* __restrict__ bi3,
                       const float* __restrict__ bi4,
                       float* __restrict__ ws) {
  const int wsel = blockIdx.z;
  const float* W = wsel == 0 ? W0 : wsel == 1 ? W1 : wsel == 2 ? W2 : wsel == 3 ? W3 : W4;
  const float* bias = wsel == 0 ? bi0 : wsel == 1 ? bi1 : wsel == 2 ? bi2 : wsel == 3 ? bi3 : bi4;
  float* out = ws + (size_t)wsel * 196608u;

  const int m0 = blockIdx.x * 64;
  const int c0 = blockIdx.y * 64;
  const int nblk = c0 >> 6;
  __shared__ float As[16 * 68], Bs[16 * 68];
  const int t = threadIdx.x;
  const int tm4 = (t >> 4) * 4, tn4 = (t & 15) * 4;
  float acc[4][4] = {};

  for (int k0 = 0; k0 < 512; k0 += 16) {
    load_At(x + m0 * 512 + k0, 512, As, t);
#pragma unroll
    for (int it = 0; it < 4; ++it) {
      int kk = (t >> 6) + it * 4, cc = t & 63;
      Bs[kk * 68 + cc] = W[nblk * 32768 + (k0 + kk) * 64 + cc];
    }
    __syncthreads();
    mm_acc16(As, Bs, acc, tm4, tn4);
    __syncthreads();
  }
  const float4 bv = *(const float4*)&bias[c0 + tn4];
#pragma unroll
  for (int i = 0; i < 4; ++i) {
    float4 v;
    v.x = acc[i][0] + bv.x; v.y = acc[i][1] + bv.y; v.z = acc[i][2] + bv.z; v.w = acc[i][3] + bv.w;
    *(float4*)&out[(m0 + tm4 + i) * 512 + c0 + tn4] = v;
  }
}

// ---------------- k_bsum ----------------

__global__ void k_bsum(const float* __restrict__ bp, float* __restrict__ out) {
  int idx = blockIdx.x * 256 + threadIdx.x;
  if (idx < 24576) {
    int bq = idx >> 6, j = idx & 63;
    float s = 0.f;
#pragma unroll
    for (int n = 0; n < 8; ++n) s += bp[bq * 512 + n * 64 + j];
    out[idx] = s;
  }
}

// ---------------- k_step1 ----------------

__global__ void k_step1(const float* __restrict__ Cp, const float* __restrict__ WK,
                        float* __restrict__ S1) {
  const int m0 = blockIdx.x * 64, c0 = blockIdx.y * 64;
  __shared__ float As[16 * 68], Bs[16 * 68];
  const int t = threadIdx.x;
  const int tm4 = (t >> 4) * 4, tn4 = (t & 15) * 4;
  float acc[4][4] = {};
  for (int k0 = 0; k0 < 512; k0 += 16) {
    load_At(Cp + m0 * 512 + k0, 512, As, t);
#pragma unroll
    for (int it = 0; it < 4; ++it) {
      int kk = t & 15, cc = (t >> 4) + it * 16;
      int k = k0 + kk;
      Bs[kk * 68 + cc] = WK[(k >> 6) * 262144 + (c0 + cc) * 64 + (k & 63)];
    }
    __syncthreads();
    mm_acc16(As, Bs, acc, tm4, tn4);
    __syncthreads();
  }
#pragma unroll
  for (int i = 0; i < 4; ++i) {
    float4 v; v.x = acc[i][0]; v.y = acc[i][1]; v.z = acc[i][2]; v.w = acc[i][3];
    *(float4*)&S1[(size_t)(m0 + tm4 + i) * 4096 + c0 + tn4] = v;
  }
}

// ---------------- k_step2 ----------------

__global__ void k_step2(const float* __restrict__ S1, const float* __restrict__ BS,
                        float* __restrict__ S2) {
  const int b = blockIdx.z;
  const int m0 = blockIdx.x * 64, c0 = blockIdx.y * 64;
  const float* A = S1 + (size_t)b * 786432u;
  const float* Bb = BS + b * 12288;
  float* C = S2 + (size_t)b * 2359296u;
  __shared__ float As[16 * 68], Bs[16 * 68];
  const int t = threadIdx.x;
  const int tm4 = (t >> 4) * 4, tn4 = (t & 15) * 4;
  float acc[4][4] = {};
  for (int k0 = 0; k0 < 64; k0 += 16) {
    load_At(A + m0 * 64 + k0, 64, As, t);
#pragma unroll
    for (int it = 0; it < 4; ++it) {
      int kk = t & 15, cc = (t >> 4) + it * 16;
      Bs[kk * 68 + cc] = Bb[(c0 + cc) * 64 + k0 + kk];
    }
    __syncthreads();
    mm_acc16(As, Bs, acc, tm4, tn4);
    __syncthreads();
  }
#pragma unroll
  for (int i = 0; i < 4; ++i) {
    float4 v; v.x = acc[i][0]; v.y = acc[i][1]; v.z = acc[i][2]; v.w = acc[i][3];
    *(float4*)&C[(size_t)(m0 + tm4 + i) * 192 + c0 + tn4] = v;
  }
}

// ---------------- k_attn: bf16 MFMA version ----------------
// LDS byte offsets (dynamic, total 108544 B)
#define X_ST2T 0u        // bf16 [192][72]  st2_t[q][i]
#define X_ET   27648u    // bf16 [64][200]  e_t[g][q]
#define X_E    53248u    // bf16 [64][200]  E[p_loc][q]
#define X_AS   78848u    // bf16 [64][72]   a_s[p_loc][i]
#define X_DT   88064u    // bf16 [64][72]   d_t[h][p_loc]
#define X_FT   97280u    // bf16 [64][72]   F_t[g][p_loc]
#define X_RED  106496u   // f32  [512]
#define X_TOT  108544u
#define X_US   0u        // f32 [64][66] alias over st2_t (epilogue)
#define X_RZ   27648u    // f32 [32][64] alias over e_t   (epilogue)

extern "C" __global__ void __launch_bounds__(512, 1)
k_attn(const float* __restrict__ st2, const float* __restrict__ eproj,
       const float* __restrict__ aproj, const float* __restrict__ dproj,
       const float* __restrict__ WV, float* __restrict__ zout) {
  extern __shared__ char smc[];
  unsigned short* lus = (unsigned short*)smc;
  float* lf = (float*)smc;
  const int bn = blockIdx.x;               // bid%8 == n -> head pinned to one XCD
  const int r = 191 - (int)blockIdx.y;     // heavy blocks first
  const int b = bn >> 3, n = bn & 7;
  const int t = threadIdx.x;
  const int lane = t & 63, w = t >> 6;
  const int l15 = lane & 15, kg = lane >> 4;

  const float* st2g = st2 + (size_t)b * 2359296u + (size_t)r * 12288u;  // [i][q]
  const float* eg = eproj + (size_t)b * 98304u + n * 64;
  const float* ag = aproj + (size_t)b * 98304u + n * 64;
  const float* dg = dproj + (size_t)b * 98304u + n * 64;

  // ---- prologue staging: st2_t[q][i], e_t[g][q] ----
  for (int idx = t; idx < 12288; idx += 512) {
    int i = idx / 192, q = idx - i * 192;
    lus[(X_ST2T >> 1) + q * 72 + i] = f2bf(st2g[idx]);
  }
  for (int idx = t; idx < 12288; idx += 512) {
    int q = idx >> 6, g = idx & 63;
    lus[(X_ET >> 1) + g * 200 + q] = f2bf(eg[q * 512 + g]);
  }

  float Dpart = 0.f;
  f4v U0 = {0.f, 0.f, 0.f, 0.f};
  f4v U1 = {0.f, 0.f, 0.f, 0.f};
  const int ptiles = (r + 63) >> 6;

  for (int pt_i = 0; pt_i < ptiles; ++pt_i) {
    const int p0 = pt_i << 6;
    // stage a_s[p][i] (natural), d_t[h][p] (transposed)
    for (int idx = t; idx < 4096; idx += 512) {
      int p = idx >> 6, c = idx & 63;
      float av = ag[(p0 + p) * 512 + c];
      float dv = dg[(p0 + p) * 512 + c];
      lus[(X_AS >> 1) + p * 72 + c] = f2bf(av);
      lus[(X_DT >> 1) + c * 72 + p] = f2bf(dv);
    }
    __syncthreads();

    // ---- GEMM1': S_T[q][p] = st2_t[q][i] . a_s[p][i]; mask+exp -> E[p][q] ----
#pragma unroll
    for (int s = 0; s < 6; ++s) {
      const int tid = w + 8 * s, qt = tid >> 2, pt = tid & 3;
      f4v acc = {0.f, 0.f, 0.f, 0.f};
#pragma unroll
      for (int kb = 0; kb < 2; ++kb) {
        const s8v A = *(const s8v*)&lus[(X_ST2T >> 1) + (qt * 16 + l15) * 72 + kb * 32 + kg * 8];
        const s8v Bf = *(const s8v*)&lus[(X_AS >> 1) + (pt * 16 + l15) * 72 + kb * 32 + kg * 8];
        acc = __builtin_amdgcn_mfma_f32_16x16x32_bf16(A, Bf, acc, 0, 0, 0);
      }
      const int p_loc = pt * 16 + l15, p = p0 + p_loc;
      short4 pk;
      {
        float Ev0 = 0.f, Ev1 = 0.f, Ev2 = 0.f, Ev3 = 0.f;
        const int q0 = qt * 16 + kg * 4;
        if (p < r) {
          if (q0 + 0 > p) { Ev0 = __expf(acc[0] * 0.015625f); Dpart += Ev0; }
          if (q0 + 1 > p) { Ev1 = __expf(acc[1] * 0.015625f); Dpart += Ev1; }
          if (q0 + 2 > p) { Ev2 = __expf(acc[2] * 0.015625f); Dpart += Ev2; }
          if (q0 + 3 > p) { Ev3 = __expf(acc[3] * 0.015625f); Dpart += Ev3; }
        }
        pk.x = (short)f2bf(Ev0); pk.y = (short)f2bf(Ev1);
        pk.z = (short)f2bf(Ev2); pk.w = (short)f2bf(Ev3);
      }
      *(short4*)&lus[(X_E >> 1) + p_loc * 200 + qt * 16 + kg * 4] = pk;
    }
    __syncthreads();

    // ---- GEMM2: F[p][g] = E[p][q] . e_t[g][q] -> F_t[g][p] ----
#pragma unroll
    for (int s = 0; s < 2; ++s) {
      const int tid = w + 8 * s, mt = tid >> 2, nt = tid & 3;
      f4v acc = {0.f, 0.f, 0.f, 0.f};
#pragma unroll
      for (int kb = 0; kb < 6; ++kb) {
        const s8v A = *(const s8v*)&lus[(X_E >> 1) + (mt * 16 + l15) * 200 + kb * 32 + kg * 8];
        const s8v Bf = *(const s8v*)&lus[(X_ET >> 1) + (nt * 16 + l15) * 200 + kb * 32 + kg * 8];
        acc = __builtin_amdgcn_mfma_f32_16x16x32_bf16(A, Bf, acc, 0, 0, 0);
      }
      short4 pk;
      pk.x = (short)f2bf(acc[0]); pk.y = (short)f2bf(acc[1]);
      pk.z = (short)f2bf(acc[2]); pk.w = (short)f2bf(acc[3]);
      *(short4*)&lus[(X_FT >> 1) + (nt * 16 + l15) * 72 + mt * 16 + kg * 4] = pk;
    }
    __syncthreads();

    // ---- GEMM3: U[h][g] += d_t[h][p] . F_t[g][p] ----
    {
      const int tid0 = w, ht0 = tid0 >> 2, gt0 = tid0 & 3;
#pragma unroll
      for (int kb = 0; kb < 2; ++kb) {
        const s8v A = *(const s8v*)&lus[(X_DT >> 1) + (ht0 * 16 + l15) * 72 + kb * 32 + kg * 8];
        const s8v Bf = *(const s8v*)&lus[(X_FT >> 1) + (gt0 * 16 + l15) * 72 + kb * 32 + kg * 8];
        U0 = __builtin_amdgcn_mfma_f32_16x16x32_bf16(A, Bf, U0, 0, 0, 0);
      }
      const int tid1 = w + 8, ht1 = tid1 >> 2, gt1 = tid1 & 3;
#pragma unroll
      for (int kb = 0; kb < 2; ++kb) {
        const s8v A = *(const s8v*)&lus[(X_DT >> 1) + (ht1 * 16 + l15) * 72 + kb * 32 + kg * 8];
        const s8v Bf = *(const s8v*)&lus[(X_FT >> 1) + (gt1 * 16 + l15) * 72 + kb * 32 + kg * 8];
        U1 = __builtin_amdgcn_mfma_f32_16x16x32_bf16(A, Bf, U1, 0, 0, 0);
      }
    }
    __syncthreads();
  }

  // ---- denominator reduction ----
  lf[(X_RED >> 2) + t] = Dpart;
  __syncthreads();
  for (int off = 256; off > 0; off >>= 1) {
    if (t < off) lf[(X_RED >> 2) + t] += lf[(X_RED >> 2) + t + off];
    __syncthreads();
  }
  const float Dfull = lf[X_RED >> 2];
  const float invD = Dfull > 0.f ? 1.f / Dfull : 0.f;  // r==0 -> all zeros
  __syncthreads();  // st2_t / e_t regions now reusable

  // ---- U (scaled) -> U_s[g][66+h] ----
  {
    const int ht0 = w >> 2, gt0 = w & 3;
#pragma unroll
    for (int j = 0; j < 4; ++j)
      lf[(X_US >> 2) + (gt0 * 16 + l15) * 66 + ht0 * 16 + kg * 4 + j] = U0[j] * invD;
    const int ht1 = (w + 8) >> 2, gt1 = (w + 8) & 3;
#pragma unroll
    for (int j = 0; j < 4; ++j)
      lf[(X_US >> 2) + (gt1 * 16 + l15) * 66 + ht1 * 16 + kg * 4 + j] = U1[j] * invD;
  }
  __syncthreads();

  // ---- epilogue: z[k] = sum_{h,g} U_s[g][h] * WV[n][h*4096 + g*64 + k] ----
  const float* WVn = WV + (size_t)n * 262144u;
  const int k4 = (t & 15) * 4, hh = t >> 4;  // 32 hh-groups x 2 h each
  float zx = 0.f, zy = 0.f, zz = 0.f, zw = 0.f;
#pragma unroll
  for (int hi = 0; hi < 2; ++hi) {
    const int h = hh * 2 + hi;
    const float* wr = WVn + (size_t)h * 4096 + k4;
    for (int g = 0; g < 64; ++g) {
      const float u = lf[(X_US >> 2) + g * 66 + h];
      const float4 wv = *(const float4*)(wr + g * 64);
      zx += u * wv.x; zy += u * wv.y; zz += u * wv.z; zw += u * wv.w;
    }
  }
  { float4 zp; zp.x = zx; zp.y = zy; zp.z = zz; zp.w = zw;
    *(float4*)&lf[(X_RZ >> 2) + hh * 64 + k4] = zp; }
  __syncthreads();
  if (t < 64) {
    float z = 0.f;
#pragma unroll 8
    for (int c = 0; c < 32; ++c) z += lf[(X_RZ >> 2) + c * 64 + t];
    zout[(size_t)(b * 192 + r) * 512 + n * 64 + t] = z;
  }
}

// ---------------- k_out ----------------

__global__ void k_out(const float* __restrict__ Z, const float* __restrict__ WO,
                      const float* __restrict__ bO, float* __restrict__ out) {
  const int m0 = blockIdx.x * 64, c0 = blockIdx.y * 64;
  __shared__ float As[16 * 68], Bs[16 * 68];
  const int t = threadIdx.x;
  const int tm4 = (t >> 4) * 4, tn4 = (t & 15) * 4;
  float acc[4][4] = {};
  for (int k0 = 0; k0 < 512; k0 += 16) {
    load_At(Z + m0 * 512 + k0, 512, As, t);
#pragma unroll
    for (int it = 0; it < 4; ++it) {
      int kk = (t >> 6) + it * 4, cc = t & 63;
      Bs[kk * 68 + cc] = WO[(k0 + kk) * 512 + c0 + cc];
    }
    __syncthreads();
    mm_acc16(As, Bs, acc, tm4, tn4);
    __syncthreads();
  }
  const float4 bv = *(const float4*)&bO[c0 + tn4];
#pragma unroll
  for (int i = 0; i < 4; ++i) {
    float4 v;
    v.x = acc[i][0] + bv.x; v.y = acc[i][1] + bv.y; v.z = acc[i][2] + bv.z; v.w = acc[i][3] + bv.w;
    *(float4*)&out[(m0 + tm4 + i) * 512 + c0 + tn4] = v;
  }
}

// ---------------- launch ----------------

extern "C" void kernel_launch(void* const* d_in, const int* in_sizes, int n_in,
                              void* d_out, int out_size, void* d_ws, size_t ws_size,
                              hipStream_t stream) {
  const float* x  = (const float*)d_in[0];
  const float* WA = (const float*)d_in[1];
  const float* WB = (const float*)d_in[2];
  const float* WC = (const float*)d_in[3];
  const float* WD = (const float*)d_in[4];
  const float* WE = (const float*)d_in[5];
  const float* WK = (const float*)d_in[6];
  const float* WV = (const float*)d_in[7];
  const float* WO = (const float*)d_in[8];
  const float* bA = (const float*)d_in[9];
  const float* bB = (const float*)d_in[10];
  const float* bC = (const float*)d_in[11];
  const float* bD = (const float*)d_in[12];
  const float* bE = (const float*)d_in[13];
  const float* bO = (const float*)d_in[14];
  float* ws = (float*)d_ws;
  float* out = (float*)d_out;

  dim3 blk(256);
  k_proj<<<dim3(6, 8, 5), blk, 0, stream>>>(x, WA, WB, WC, WD, WE, bA, bB, bC, bD, bE, ws);
  k_bsum<<<dim3(96), blk, 0, stream>>>(ws + OFF_Bp, ws + OFF_BSUM);
  k_step1<<<dim3(6, 64), blk, 0, stream>>>(ws + OFF_C, WK, ws + OFF_S1);
  k_step2<<<dim3(192, 3, 2), blk, 0, stream>>>(ws + OFF_S1, ws + OFF_BSUM, ws + OFF_S2);

  hipFuncSetAttribute((const void*)k_attn, hipFuncAttributeMaxDynamicSharedMemorySize, X_TOT);
  k_attn<<<dim3(16, 192), dim3(512), X_TOT, stream>>>(ws + OFF_S2, ws + OFF_E, ws + OFF_A,
                                                      ws + OFF_D, WV, ws + OFF_Z);

  k_out<<<dim3(6, 8), blk, 0, stream>>>(ws + OFF_Z, WO, bO, out);
}